// Round 11
// baseline (787.082 us; speedup 1.0000x reference)
//
#include <hip/hip_runtime.h>

#define NN 50000
#define NE 600000

typedef __attribute__((ext_vector_type(8))) short short8;
typedef __attribute__((ext_vector_type(4))) float f32x4;

#define SWZ(row) ((((row) & 7) << 4) ^ (((row) & 8) << 2))

__device__ __forceinline__ float silu_f(float x) { return x / (1.0f + __expf(-x)); }

__device__ __forceinline__ unsigned short f2bf(float f) {
    unsigned u = __builtin_bit_cast(unsigned, f);
    unsigned r = u + 0x7FFFu + ((u >> 16) & 1u);   // RNE
    return (unsigned short)(r >> 16);
}

// LDS-only barrier (no vmcnt drain) — atomics/stores stay in flight.
__device__ __forceinline__ void lds_barrier() {
    asm volatile("s_waitcnt lgkmcnt(0)" ::: "memory");
    __builtin_amdgcn_s_barrier();
    asm volatile("" ::: "memory");
}

// 4x4 transpose across the 4 lanes of a quad (p = lane&3).
__device__ __forceinline__ void xpose4(float v[4]) {
    const int p = threadIdx.x & 3;
    float s0 = (p & 1) ? v[0] : v[1];
    float s1 = (p & 1) ? v[2] : v[3];
    s0 = __shfl_xor(s0, 1);
    s1 = __shfl_xor(s1, 1);
    float w0 = (p & 1) ? s0 : v[0];
    float w1 = (p & 1) ? v[1] : s0;
    float w2 = (p & 1) ? s1 : v[2];
    float w3 = (p & 1) ? v[3] : s1;
    float t0 = (p & 2) ? w0 : w2;
    float t1 = (p & 2) ? w1 : w3;
    t0 = __shfl_xor(t0, 2);
    t1 = __shfl_xor(t1, 2);
    v[0] = (p & 2) ? t0 : w0;
    v[2] = (p & 2) ? w2 : t0;
    v[1] = (p & 2) ? t1 : w1;
    v[3] = (p & 2) ? w3 : t1;
}

__device__ __forceinline__ unsigned cvt_pk_bf16(float lo, float hi) {
    unsigned r;
    asm("v_cvt_pk_bf16_f32 %0, %1, %2" : "=v"(r) : "v"(lo), "v"(hi));
    return r;
}

// ---------------------------------------------------------------------------
// K0: h (fp32) -> h_bf16
// ---------------------------------------------------------------------------
__global__ __launch_bounds__(512) void k_prep(const float* __restrict__ h,
                                              unsigned short* __restrict__ hb)
{
    const int nchunks = NN * 128 / 8;   // 800000
    for (int i = blockIdx.x * blockDim.x + threadIdx.x; i < nchunks;
         i += gridDim.x * blockDim.x) {
        const float4* p = (const float4*)(h + (size_t)i * 8);
        float4 x = p[0], y = p[1];
        short8 v;
        v[0] = f2bf(x.x); v[1] = f2bf(x.y); v[2] = f2bf(x.z); v[3] = f2bf(x.w);
        v[4] = f2bf(y.x); v[5] = f2bf(y.y); v[6] = f2bf(y.z); v[7] = f2bf(y.w);
        *(short8*)(hb + (size_t)i * 8) = v;
    }
}

// ---------------------------------------------------------------------------
// CSR build: deg count -> 1-block scan -> scatter
// ---------------------------------------------------------------------------
__global__ __launch_bounds__(256) void k_deg(const int* __restrict__ ei,
                                             int* __restrict__ deg)
{
    for (int e = blockIdx.x * 256 + threadIdx.x; e < NE; e += gridDim.x * 256)
        atomicAdd(&deg[ei[e]], 1);
}

__global__ __launch_bounds__(1024) void k_scan(const int* __restrict__ deg,
                                               int* __restrict__ rowptr,
                                               int* __restrict__ cursor)
{
    __shared__ int sb[1024];
    const int t = threadIdx.x;
    const int CH = 49;
    const int base = t * CH;
    int s = 0;
    for (int j = 0; j < CH; ++j) {
        int idx = base + j;
        if (idx < NN) s += deg[idx];
    }
    sb[t] = s;
    __syncthreads();
    for (int off = 1; off < 1024; off <<= 1) {
        int v = (t >= off) ? sb[t - off] : 0;
        __syncthreads();
        sb[t] += v;
        __syncthreads();
    }
    int run = sb[t] - s;
    for (int j = 0; j < CH; ++j) {
        int idx = base + j;
        if (idx < NN) {
            rowptr[idx] = run;
            cursor[idx] = run;
            run += deg[idx];
        }
    }
    if (t == 1023) rowptr[NN] = sb[1023];
}

__global__ __launch_bounds__(256) void k_scatter(const int* __restrict__ ei,
                                                 int* __restrict__ cursor,
                                                 int* __restrict__ elist)
{
    for (int e = blockIdx.x * 256 + threadIdx.x; e < NE; e += gridDim.x * 256) {
        int pos = atomicAdd(&cursor[ei[e]], 1);
        elist[pos] = e;
    }
}

// ---------------------------------------------------------------------------
// K1: edge MLP (CSR order), T14 async-stage: the 8-line hb gather for tile
// t+stride is issued right after B1(t) into registers, retiring under
// GEMM1/GEMM2/seg-reduce; ds_write happens at the top of the next iteration.
// Phases per 64-edge tile: [meta + ds_write pf] B1 [issue pf(t+1); G1+epi1]
// B2 [G2+epi2: ef nt + EF->A1s] B3 [seg-reduce -> agg atomics] B4.
// ---------------------------------------------------------------------------
__global__ __launch_bounds__(512, 6) void k_edge(
    const unsigned short* __restrict__ hb, const float* __restrict__ coord,
    const int* __restrict__ ei, const int* __restrict__ elist,
    const float* __restrict__ w_e1, const float* __restrict__ b_e1,
    const float* __restrict__ w_e2, const float* __restrict__ b_e2,
    float* __restrict__ ef, float* __restrict__ agg)
{
    __shared__ unsigned short A1s[64 * 256];    // 32 KB (h-pair; later EF bf16)
    __shared__ unsigned short A2s[64 * 128];    // 16 KB (t1 bf16)
    __shared__ float rad[64];
    __shared__ int   es_s[64];
    __shared__ int   seg_start[65];
    __shared__ int   seg_row[64];
    __shared__ int   nseg_s;

    const int tid  = threadIdx.x;
    const int wv   = tid >> 6, lane = tid & 63;
    const int l4   = lane >> 4, li = lane & 15;
    const int n    = wv * 16 + li;              // this wave's output column

    short8 bw1[8], bw2[4];
    #pragma unroll
    for (int ks = 0; ks < 8; ++ks) {
        short8 t;
        #pragma unroll
        for (int j = 0; j < 8; ++j) t[j] = f2bf(w_e1[(ks * 32 + l4 * 8 + j) * 128 + n]);
        bw1[ks] = t;
    }
    #pragma unroll
    for (int ks = 0; ks < 4; ++ks) {
        short8 t;
        #pragma unroll
        for (int j = 0; j < 8; ++j) t[j] = f2bf(w_e2[(ks * 32 + l4 * 8 + j) * 128 + n]);
        bw2[ks] = t;
    }
    const float wradv = w_e1[256 * 128 + n];
    const float b1v = b_e1[n], b2v = b_e2[n];

    const f32x4 z4 = {0.f, 0.f, 0.f, 0.f};
    const int colb = wv * 16 + (li >> 2) * 4;   // transposed col base
    const int pp   = li & 3;
    const int le   = tid >> 3;                  // edge slot this thread stages
    const int ch0  = tid & 7;                   // chunk group
    const int ntiles = NE / 64;
    const int tstep  = gridDim.x;

    // ---- prologue: gather first tile into registers ----
    short8 pf[4];
    {
        int e = elist[blockIdx.x * 64 + le];
        int r = ei[e], c = ei[NE + e];
        const unsigned short* hr = hb + (size_t)r * 128;
        const unsigned short* hc = hb + (size_t)c * 128;
        #pragma unroll
        for (int i = 0; i < 4; ++i) {
            int chunk = i * 8 + ch0;
            pf[i] = (chunk < 16) ? *(const short8*)(hr + chunk * 8)
                                 : *(const short8*)(hc + (chunk - 16) * 8);
        }
    }

    for (int t = blockIdx.x; t < ntiles; t += tstep) {
        const int ebase = t * 64;
        // ---- wave 0: edge ids, radial, segment table ----
        if (tid < 64) {
            int e = elist[ebase + tid];
            int r = ei[e], c = ei[NE + e];
            es_s[tid] = e;
            float dx = coord[r * 3 + 0] - coord[c * 3 + 0];
            float dy = coord[r * 3 + 1] - coord[c * 3 + 1];
            float dz = coord[r * 3 + 2] - coord[c * 3 + 2];
            rad[tid] = dx * dx + dy * dy + dz * dz;
            int prev = __shfl_up(r, 1);
            bool flag = (lane == 0) || (r != prev);
            unsigned long long mask = __ballot(flag);
            if (flag) {
                int pos = __popcll(mask & ((1ull << lane) - 1ull));
                seg_start[pos] = lane;
                seg_row[pos]   = r;
            }
            if (lane == 0) {
                int ns = __popcll(mask);
                nseg_s = ns;
                seg_start[ns] = 64;
            }
        }
        // ---- commit prefetched A1 tile: regs -> LDS ----
        #pragma unroll
        for (int i = 0; i < 4; ++i) {
            int chunk = i * 8 + ch0;
            int off = le * 512 + ((chunk * 16) ^ SWZ(le));
            *(short8*)((char*)A1s + off) = pf[i];
        }
        lds_barrier();   // B1

        // ---- issue next tile's gather (retires under G1/G2/seg-reduce) ----
        {
            int tn = t + tstep;
            if (tn < ntiles) {
                int e = elist[tn * 64 + le];
                int r = ei[e], c = ei[NE + e];
                const unsigned short* hr = hb + (size_t)r * 128;
                const unsigned short* hc = hb + (size_t)c * 128;
                #pragma unroll
                for (int i = 0; i < 4; ++i) {
                    int chunk = i * 8 + ch0;
                    pf[i] = (chunk < 16) ? *(const short8*)(hr + chunk * 8)
                                         : *(const short8*)(hc + (chunk - 16) * 8);
                }
            }
        }

        // ---- GEMM1: [64 x 256] @ [256 x 16] ----
        f32x4 acc[4];
        acc[0] = z4; acc[1] = z4; acc[2] = z4; acc[3] = z4;
        for (int ks = 0; ks < 8; ++ks) {
            const int kb = ks * 64 + l4 * 16;
            #pragma unroll
            for (int mf = 0; mf < 4; ++mf) {
                int row = mf * 16 + li;
                short8 a = *(const short8*)((const char*)A1s + row * 512 + (kb ^ SWZ(row)));
                acc[mf] = __builtin_amdgcn_mfma_f32_16x16x32_bf16(a, bw1[ks], acc[mf], 0, 0, 0);
            }
        }
        // epi1: bias + radial rank-1 + silu -> transpose -> packed b64 to A2s
        #pragma unroll
        for (int mf = 0; mf < 4; ++mf) {
            float4 rr = *(const float4*)&rad[mf * 16 + l4 * 4];
            float v[4];
            v[0] = silu_f(acc[mf][0] + rr.x * wradv + b1v);
            v[1] = silu_f(acc[mf][1] + rr.y * wradv + b1v);
            v[2] = silu_f(acc[mf][2] + rr.z * wradv + b1v);
            v[3] = silu_f(acc[mf][3] + rr.w * wradv + b1v);
            xpose4(v);
            int row = mf * 16 + l4 * 4 + pp;
            uint2 d;
            d.x = cvt_pk_bf16(v[0], v[1]);
            d.y = cvt_pk_bf16(v[2], v[3]);
            *(uint2*)((char*)A2s + row * 256 + ((colb * 2) ^ SWZ(row))) = d;
        }
        lds_barrier();   // B2: A2s ready; A1s reads done

        // ---- GEMM2: [64 x 128] @ [128 x 16] ----
        acc[0] = z4; acc[1] = z4; acc[2] = z4; acc[3] = z4;
        for (int ks = 0; ks < 4; ++ks) {
            const int kb = ks * 64 + l4 * 16;
            #pragma unroll
            for (int mf = 0; mf < 4; ++mf) {
                int row = mf * 16 + li;
                short8 a = *(const short8*)((const char*)A2s + row * 256 + (kb ^ SWZ(row)));
                acc[mf] = __builtin_amdgcn_mfma_f32_16x16x32_bf16(a, bw2[ks], acc[mf], 0, 0, 0);
            }
        }
        // epi2: bias+silu -> transpose -> EF b64 to A1s + ef f32x4 nt-store
        #pragma unroll
        for (int mf = 0; mf < 4; ++mf) {
            float v[4];
            v[0] = silu_f(acc[mf][0] + b2v);
            v[1] = silu_f(acc[mf][1] + b2v);
            v[2] = silu_f(acc[mf][2] + b2v);
            v[3] = silu_f(acc[mf][3] + b2v);
            xpose4(v);
            int row = mf * 16 + l4 * 4 + pp;
            uint2 d;
            d.x = cvt_pk_bf16(v[0], v[1]);
            d.y = cvt_pk_bf16(v[2], v[3]);
            *(uint2*)((char*)A1s + row * 256 + ((colb * 2) ^ SWZ(row))) = d;
            int e = es_s[row];
            f32x4 o = {v[0], v[1], v[2], v[3]};
            __builtin_nontemporal_store(o, (f32x4*)&ef[(size_t)e * 128 + colb]);
        }
        lds_barrier();   // B3: EF(A1s) complete

        // ---- seg-reduce: thread = (col-group of 4, seg slot) ----
        {
            const int cg = tid & 31;          // cols 4cg..4cg+3
            const int ns = nseg_s;
            for (int s = tid >> 5; s < ns; s += 16) {
                int i0 = seg_start[s], i1 = seg_start[s + 1];
                float s0 = 0.f, s1 = 0.f, s2 = 0.f, s3 = 0.f;
                for (int i = i0; i < i1; ++i) {
                    uint2 d = *(const uint2*)((const char*)A1s + i * 256 + ((cg * 8) ^ SWZ(i)));
                    s0 += __builtin_bit_cast(float, d.x << 16);
                    s1 += __builtin_bit_cast(float, d.x & 0xffff0000u);
                    s2 += __builtin_bit_cast(float, d.y << 16);
                    s3 += __builtin_bit_cast(float, d.y & 0xffff0000u);
                }
                float* ap = &agg[(size_t)seg_row[s] * 128 + cg * 4];
                atomicAdd(ap + 0, s0);
                atomicAdd(ap + 1, s1);
                atomicAdd(ap + 2, s2);
                atomicAdd(ap + 3, s3);
            }
        }
        lds_barrier();   // B4: A1s/seg reads done before next stage
    }
}

// ---------------------------------------------------------------------------
// K-coord: streaming coord MLP (original edge order).
//   wq = silu(ef @ w_c1 + b_c1) @ w_c2 ; tsum[row] += coord_diff * wq
// Swapped-operand GEMM: Wc1^T(A) x EF^T(B) -> edge lives in lane.
// 8 waves: edge-half (w&1)*64, feat-quarter (w>>1)*32. 2 lgkm barriers.
// ---------------------------------------------------------------------------
__global__ __launch_bounds__(512, 4) void k_coord(
    const float* __restrict__ ef, const float* __restrict__ coord,
    const int* __restrict__ ei,
    const float* __restrict__ w_c1, const float* __restrict__ b_c1,
    const float* __restrict__ w_c2,
    float* __restrict__ tsum)
{
    __shared__ unsigned short EFs[128 * 128];   // 32 KB, [edge][k] swizzled
    __shared__ float wqp[4][128];

    const int tid  = threadIdx.x;
    const int wv   = tid >> 6, lane = tid & 63;
    const int l4   = lane >> 4, li = lane & 15;
    const int eh   = (wv & 1) * 64;             // edge-half base
    const int fq   = (wv >> 1) * 32;            // feat-quarter base

    short8 wa[2][4];
    #pragma unroll
    for (int mf = 0; mf < 2; ++mf)
        #pragma unroll
        for (int ks = 0; ks < 4; ++ks) {
            short8 t;
            #pragma unroll
            for (int j = 0; j < 8; ++j)
                t[j] = f2bf(w_c1[(ks * 32 + l4 * 8 + j) * 128 + fq + mf * 16 + li]);
            wa[mf][ks] = t;
        }
    float bcv[2][4], wcv[2][4];
    #pragma unroll
    for (int mf = 0; mf < 2; ++mf)
        #pragma unroll
        for (int r = 0; r < 4; ++r) {
            int feat = fq + mf * 16 + l4 * 4 + r;
            bcv[mf][r] = b_c1[feat];
            wcv[mf][r] = w_c2[feat];
        }

    const f32x4 z4 = {0.f, 0.f, 0.f, 0.f};
    const int ntiles = (NE + 127) / 128;

    for (int t = blockIdx.x; t < ntiles; t += gridDim.x) {
        const int ebase = t * 128;
        // stage ef -> bf16 LDS: thread = (edge row tid>>2, 32-col chunk tid&3)
        {
            int row = tid >> 2;
            int e = ebase + row;
            int cb = (tid & 3) * 32;
            #pragma unroll
            for (int i = 0; i < 2; ++i) {
                int c0 = cb + i * 16;
                short8 v;
                if (e < NE) {
                    const float4* p = (const float4*)(ef + (size_t)e * 128 + c0);
                    float4 x = p[0], y = p[1];
                    v[0] = f2bf(x.x); v[1] = f2bf(x.y); v[2] = f2bf(x.z); v[3] = f2bf(x.w);
                    v[4] = f2bf(y.x); v[5] = f2bf(y.y); v[6] = f2bf(y.z); v[7] = f2bf(y.w);
                } else v = (short8)0;
                *(short8*)((char*)EFs + row * 256 + ((c0 * 2) ^ SWZ(row))) = v;
                int c1 = c0 + 8;
                short8 w;
                if (e < NE) {
                    const float4* q = (const float4*)(ef + (size_t)e * 128 + c1);
                    float4 x = q[0], y = q[1];
                    w[0] = f2bf(x.x); w[1] = f2bf(x.y); w[2] = f2bf(x.z); w[3] = f2bf(x.w);
                    w[4] = f2bf(y.x); w[5] = f2bf(y.y); w[6] = f2bf(y.z); w[7] = f2bf(y.w);
                } else w = (short8)0;
                *(short8*)((char*)EFs + row * 256 + ((c1 * 2) ^ SWZ(row))) = w;
            }
        }
        lds_barrier();   // B1

        f32x4 acc[2][4];
        #pragma unroll
        for (int mf = 0; mf < 2; ++mf)
            #pragma unroll
            for (int nf = 0; nf < 4; ++nf) acc[mf][nf] = z4;
        for (int ks = 0; ks < 4; ++ks) {
            const int kb = ks * 64 + l4 * 16;
            #pragma unroll
            for (int nf = 0; nf < 4; ++nf) {
                int edge = eh + nf * 16 + li;
                short8 b = *(const short8*)((const char*)EFs + edge * 256 + (kb ^ SWZ(edge)));
                #pragma unroll
                for (int mf = 0; mf < 2; ++mf)
                    acc[mf][nf] = __builtin_amdgcn_mfma_f32_16x16x32_bf16(
                        wa[mf][ks], b, acc[mf][nf], 0, 0, 0);
            }
        }
        #pragma unroll
        for (int nf = 0; nf < 4; ++nf) {
            float p = 0.f;
            #pragma unroll
            for (int mf = 0; mf < 2; ++mf)
                #pragma unroll
                for (int r = 0; r < 4; ++r)
                    p += silu_f(acc[mf][nf][r] + bcv[mf][r]) * wcv[mf][r];
            p += __shfl_xor(p, 16);
            p += __shfl_xor(p, 32);
            if (l4 == 0) wqp[wv >> 1][eh + nf * 16 + li] = p;
        }
        lds_barrier();   // B2

        if (tid < 128) {
            float wq = wqp[0][tid] + wqp[1][tid] + wqp[2][tid] + wqp[3][tid];
            int e = ebase + tid;
            if (e < NE) {
                int r = ei[e], c = ei[NE + e];
                float dx = coord[r * 3 + 0] - coord[c * 3 + 0];
                float dy = coord[r * 3 + 1] - coord[c * 3 + 1];
                float dz = coord[r * 3 + 2] - coord[c * 3 + 2];
                atomicAdd(&tsum[r * 3 + 0], dx * wq);
                atomicAdd(&tsum[r * 3 + 1], dy * wq);
                atomicAdd(&tsum[r * 3 + 2], dz * wq);
            }
        }
        // wqp re-written only after B1(t+1); EFs re-staged after B2 — safe.
    }
}

// ---------------------------------------------------------------------------
// K2: fused node MLP + coord_new. Packed epilogues, 2 lgkm barriers.
// ---------------------------------------------------------------------------
__global__ __launch_bounds__(512, 8) void k_node(
    const unsigned short* __restrict__ hb, const float* __restrict__ h,
    const float* __restrict__ agg,
    const float* __restrict__ w_n1, const float* __restrict__ b_n1,
    const float* __restrict__ w_n2, const float* __restrict__ b_n2,
    const float* __restrict__ coord, const float* __restrict__ tsum,
    const int* __restrict__ rowptr,
    float* __restrict__ h_new, float* __restrict__ coord_new)
{
    __shared__ unsigned short As[64 * 256];     // 32 KB
    __shared__ unsigned short Us[64 * 128];     // 16 KB

    const int tid  = threadIdx.x;
    const int wv   = tid >> 6, lane = tid & 63;
    const int l4   = lane >> 4, li = lane & 15;
    const int n    = wv * 16 + li;

    short8 bw1[8], bw2[4];
    #pragma unroll
    for (int ks = 0; ks < 8; ++ks) {
        short8 t;
        #pragma unroll
        for (int j = 0; j < 8; ++j) t[j] = f2bf(w_n1[(ks * 32 + l4 * 8 + j) * 128 + n]);
        bw1[ks] = t;
    }
    #pragma unroll
    for (int ks = 0; ks < 4; ++ks) {
        short8 t;
        #pragma unroll
        for (int j = 0; j < 8; ++j) t[j] = f2bf(w_n2[(ks * 32 + l4 * 8 + j) * 128 + n]);
        bw2[ks] = t;
    }
    const float b1v = b_n1[n], b2v = b_n2[n];

    const f32x4 z4 = {0.f, 0.f, 0.f, 0.f};
    const int ntiles = (NN + 63) / 64;
    const int colb = wv * 16 + (li >> 2) * 4;
    const int pp   = li & 3;

    for (int t = blockIdx.x; t < ntiles; t += gridDim.x) {
        const int nbase = t * 64;
        {
            int ln = tid >> 3;
            int node = nbase + ln;
            #pragma unroll
            for (int i = 0; i < 4; ++i) {
                int chunk = i * 8 + (tid & 7);
                short8 v;
                if (node < NN) {
                    if (chunk < 16) {
                        v = *(const short8*)(hb + (size_t)node * 128 + chunk * 8);
                    } else {
                        const float4* p = (const float4*)(agg + (size_t)node * 128 + (chunk - 16) * 8);
                        float4 x = p[0], y = p[1];
                        v[0] = f2bf(x.x); v[1] = f2bf(x.y); v[2] = f2bf(x.z); v[3] = f2bf(x.w);
                        v[4] = f2bf(y.x); v[5] = f2bf(y.y); v[6] = f2bf(y.z); v[7] = f2bf(y.w);
                    }
                } else v = (short8)0;
                int off = ln * 512 + ((chunk * 16) ^ SWZ(ln));
                *(short8*)((char*)As + off) = v;
            }
        }
        lds_barrier();   // B1

        f32x4 acc[4];
        acc[0] = z4; acc[1] = z4; acc[2] = z4; acc[3] = z4;
        for (int ks = 0; ks < 8; ++ks) {
            const int kb = ks * 64 + l4 * 16;
            #pragma unroll
            for (int mf = 0; mf < 4; ++mf) {
                int row = mf * 16 + li;
                short8 a = *(const short8*)((const char*)As + row * 512 + (kb ^ SWZ(row)));
                acc[mf] = __builtin_amdgcn_mfma_f32_16x16x32_bf16(a, bw1[ks], acc[mf], 0, 0, 0);
            }
        }
        #pragma unroll
        for (int mf = 0; mf < 4; ++mf) {
            float v[4];
            v[0] = silu_f(acc[mf][0] + b1v);
            v[1] = silu_f(acc[mf][1] + b1v);
            v[2] = silu_f(acc[mf][2] + b1v);
            v[3] = silu_f(acc[mf][3] + b1v);
            xpose4(v);
            int row = mf * 16 + l4 * 4 + pp;
            uint2 d;
            d.x = cvt_pk_bf16(v[0], v[1]);
            d.y = cvt_pk_bf16(v[2], v[3]);
            *(uint2*)((char*)Us + row * 256 + ((colb * 2) ^ SWZ(row))) = d;
        }
        lds_barrier();   // B2

        acc[0] = z4; acc[1] = z4; acc[2] = z4; acc[3] = z4;
        for (int ks = 0; ks < 4; ++ks) {
            const int kb = ks * 64 + l4 * 16;
            #pragma unroll
            for (int mf = 0; mf < 4; ++mf) {
                int row = mf * 16 + li;
                short8 a = *(const short8*)((const char*)Us + row * 256 + (kb ^ SWZ(row)));
                acc[mf] = __builtin_amdgcn_mfma_f32_16x16x32_bf16(a, bw2[ks], acc[mf], 0, 0, 0);
            }
        }
        #pragma unroll
        for (int mf = 0; mf < 4; ++mf) {
            float v[4];
            v[0] = acc[mf][0] + b2v;
            v[1] = acc[mf][1] + b2v;
            v[2] = acc[mf][2] + b2v;
            v[3] = acc[mf][3] + b2v;
            xpose4(v);
            int row = mf * 16 + l4 * 4 + pp;
            int node = nbase + row;
            if (node < NN) {
                const f32x4 h4 = *(const f32x4*)&h[(size_t)node * 128 + colb];
                f32x4 o = {v[0] + h4.x, v[1] + h4.y, v[2] + h4.z, v[3] + h4.w};
                __builtin_nontemporal_store(o, (f32x4*)&h_new[(size_t)node * 128 + colb]);
            }
        }
        if (tid < 64) {
            int node = nbase + tid;
            if (node < NN) {
                int deg = rowptr[node + 1] - rowptr[node];
                float m = fmaxf((float)deg, 1.0f);
                coord_new[node * 3 + 0] = coord[node * 3 + 0] + tsum[node * 3 + 0] / m;
                coord_new[node * 3 + 1] = coord[node * 3 + 1] + tsum[node * 3 + 1] / m;
                coord_new[node * 3 + 2] = coord[node * 3 + 2] + tsum[node * 3 + 2] / m;
            }
        }
    }
}

extern "C" void kernel_launch(void* const* d_in, const int* in_sizes, int n_in,
                              void* d_out, int out_size, void* d_ws, size_t ws_size,
                              hipStream_t stream)
{
    const float* h     = (const float*)d_in[0];
    const float* coord = (const float*)d_in[1];
    const int*   ei    = (const int*)d_in[2];
    const float* w_e1  = (const float*)d_in[3];
    const float* b_e1  = (const float*)d_in[4];
    const float* w_e2  = (const float*)d_in[5];
    const float* b_e2  = (const float*)d_in[6];
    const float* w_n1  = (const float*)d_in[7];
    const float* b_n1  = (const float*)d_in[8];
    const float* w_n2  = (const float*)d_in[9];
    const float* b_n2  = (const float*)d_in[10];
    const float* w_c1  = (const float*)d_in[11];
    const float* b_c1  = (const float*)d_in[12];
    const float* w_c2  = (const float*)d_in[13];

    float* h_new     = (float*)d_out;
    float* coord_new = h_new + (size_t)NN * 128;
    float* ef        = coord_new + (size_t)NN * 3;

    float*          agg    = (float*)d_ws;                              // [NN*128]
    float*          tsum   = agg + (size_t)NN * 128;                    // [NN*3]
    int*            deg    = (int*)(tsum + (size_t)NN * 3);             // [NN]
    int*            rowptr = deg + NN;                                  // [NN+1]
    int*            cursor = rowptr + NN + 1;                           // [NN]
    int*            elist  = cursor + NN;                               // [NE]
    unsigned short* hb     = (unsigned short*)(elist + NE);             // [NN*128]

    hipMemsetAsync(agg, 0, ((size_t)NN * 128 + (size_t)NN * 3 + NN) * sizeof(float), stream);

    k_prep   <<<1024, 512, 0, stream>>>(h, hb);
    k_deg    <<<1024, 256, 0, stream>>>(ei, deg);
    k_scan   <<<1,   1024, 0, stream>>>(deg, rowptr, cursor);
    k_scatter<<<1024, 256, 0, stream>>>(ei, cursor, elist);
    k_edge   <<<768,  512, 0, stream>>>(hb, coord, ei, elist, w_e1, b_e1,
                                        w_e2, b_e2, ef, agg);
    k_coord  <<<1536, 512, 0, stream>>>(ef, coord, ei, w_c1, b_c1, w_c2, tsum);
    k_node   <<<768,  512, 0, stream>>>(hb, h, agg, w_n1, b_n1, w_n2, b_n2,
                                        coord, tsum, rowptr, h_new, coord_new);
}

// Round 12
// 647.792 us; speedup vs baseline: 1.2150x; 1.2150x over previous
//
#include <hip/hip_runtime.h>

#define NN 50000
#define NE 600000

typedef __attribute__((ext_vector_type(8))) short short8;
typedef __attribute__((ext_vector_type(4))) float f32x4;

#define SWZ(row) ((((row) & 7) << 4) ^ (((row) & 8) << 2))

__device__ __forceinline__ float silu_f(float x) { return x / (1.0f + __expf(-x)); }

__device__ __forceinline__ unsigned short f2bf(float f) {
    unsigned u = __builtin_bit_cast(unsigned, f);
    unsigned r = u + 0x7FFFu + ((u >> 16) & 1u);   // RNE
    return (unsigned short)(r >> 16);
}

// LDS-only barrier (no vmcnt drain) — atomics/stores stay in flight.
__device__ __forceinline__ void lds_barrier() {
    asm volatile("s_waitcnt lgkmcnt(0)" ::: "memory");
    __builtin_amdgcn_s_barrier();
    asm volatile("" ::: "memory");
}

// 4x4 transpose across the 4 lanes of a quad (p = lane&3).
__device__ __forceinline__ void xpose4(float v[4]) {
    const int p = threadIdx.x & 3;
    float s0 = (p & 1) ? v[0] : v[1];
    float s1 = (p & 1) ? v[2] : v[3];
    s0 = __shfl_xor(s0, 1);
    s1 = __shfl_xor(s1, 1);
    float w0 = (p & 1) ? s0 : v[0];
    float w1 = (p & 1) ? v[1] : s0;
    float w2 = (p & 1) ? s1 : v[2];
    float w3 = (p & 1) ? v[3] : s1;
    float t0 = (p & 2) ? w0 : w2;
    float t1 = (p & 2) ? w1 : w3;
    t0 = __shfl_xor(t0, 2);
    t1 = __shfl_xor(t1, 2);
    v[0] = (p & 2) ? t0 : w0;
    v[2] = (p & 2) ? w2 : t0;
    v[1] = (p & 2) ? t1 : w1;
    v[3] = (p & 2) ? w3 : t1;
}

__device__ __forceinline__ unsigned cvt_pk_bf16(float lo, float hi) {
    unsigned r;
    asm("v_cvt_pk_bf16_f32 %0, %1, %2" : "=v"(r) : "v"(lo), "v"(hi));
    return r;
}

// ---------------------------------------------------------------------------
// K0: h (fp32) -> h_bf16
// ---------------------------------------------------------------------------
__global__ __launch_bounds__(512) void k_prep(const float* __restrict__ h,
                                              unsigned short* __restrict__ hb)
{
    const int nchunks = NN * 128 / 8;   // 800000
    for (int i = blockIdx.x * blockDim.x + threadIdx.x; i < nchunks;
         i += gridDim.x * blockDim.x) {
        const float4* p = (const float4*)(h + (size_t)i * 8);
        float4 x = p[0], y = p[1];
        short8 v;
        v[0] = f2bf(x.x); v[1] = f2bf(x.y); v[2] = f2bf(x.z); v[3] = f2bf(x.w);
        v[4] = f2bf(y.x); v[5] = f2bf(y.y); v[6] = f2bf(y.z); v[7] = f2bf(y.w);
        *(short8*)(hb + (size_t)i * 8) = v;
    }
}

// ---------------------------------------------------------------------------
// CSR build: deg count -> 1-block scan -> scatter
// ---------------------------------------------------------------------------
__global__ __launch_bounds__(256) void k_deg(const int* __restrict__ ei,
                                             int* __restrict__ deg)
{
    for (int e = blockIdx.x * 256 + threadIdx.x; e < NE; e += gridDim.x * 256)
        atomicAdd(&deg[ei[e]], 1);
}

__global__ __launch_bounds__(1024) void k_scan(const int* __restrict__ deg,
                                               int* __restrict__ rowptr,
                                               int* __restrict__ cursor)
{
    __shared__ int sb[1024];
    const int t = threadIdx.x;
    const int CH = 49;
    const int base = t * CH;
    int s = 0;
    for (int j = 0; j < CH; ++j) {
        int idx = base + j;
        if (idx < NN) s += deg[idx];
    }
    sb[t] = s;
    __syncthreads();
    for (int off = 1; off < 1024; off <<= 1) {
        int v = (t >= off) ? sb[t - off] : 0;
        __syncthreads();
        sb[t] += v;
        __syncthreads();
    }
    int run = sb[t] - s;
    for (int j = 0; j < CH; ++j) {
        int idx = base + j;
        if (idx < NN) {
            rowptr[idx] = run;
            cursor[idx] = run;
            run += deg[idx];
        }
    }
    if (t == 1023) rowptr[NN] = sb[1023];
}

__global__ __launch_bounds__(256) void k_scatter(const int* __restrict__ ei,
                                                 int* __restrict__ cursor,
                                                 int* __restrict__ elist)
{
    for (int e = blockIdx.x * 256 + threadIdx.x; e < NE; e += gridDim.x * 256) {
        int pos = atomicAdd(&cursor[ei[e]], 1);
        elist[pos] = e;
    }
}

// ---------------------------------------------------------------------------
// K1: edge MLP (CSR order), T14 async-stage: the 8-line hb gather for tile
// t+stride is issued right after B1(t) into registers, retiring under
// GEMM1/GEMM2/seg-reduce; ds_write happens at the top of the next iteration.
// (512,4): VGPR budget 128 — bw1(32)+bw2(16)+pf(16)+acc(16)+addr fits
// spill-free (round 11's (512,6) forced VGPR=40 and spilled everything).
// ---------------------------------------------------------------------------
__global__ __launch_bounds__(512, 4) void k_edge(
    const unsigned short* __restrict__ hb, const float* __restrict__ coord,
    const int* __restrict__ ei, const int* __restrict__ elist,
    const float* __restrict__ w_e1, const float* __restrict__ b_e1,
    const float* __restrict__ w_e2, const float* __restrict__ b_e2,
    float* __restrict__ ef, float* __restrict__ agg)
{
    __shared__ unsigned short A1s[64 * 256];    // 32 KB (h-pair; later EF bf16)
    __shared__ unsigned short A2s[64 * 128];    // 16 KB (t1 bf16)
    __shared__ float rad[64];
    __shared__ int   es_s[64];
    __shared__ int   seg_start[65];
    __shared__ int   seg_row[64];
    __shared__ int   nseg_s;

    const int tid  = threadIdx.x;
    const int wv   = tid >> 6, lane = tid & 63;
    const int l4   = lane >> 4, li = lane & 15;
    const int n    = wv * 16 + li;              // this wave's output column

    short8 bw1[8], bw2[4];
    #pragma unroll
    for (int ks = 0; ks < 8; ++ks) {
        short8 t;
        #pragma unroll
        for (int j = 0; j < 8; ++j) t[j] = f2bf(w_e1[(ks * 32 + l4 * 8 + j) * 128 + n]);
        bw1[ks] = t;
    }
    #pragma unroll
    for (int ks = 0; ks < 4; ++ks) {
        short8 t;
        #pragma unroll
        for (int j = 0; j < 8; ++j) t[j] = f2bf(w_e2[(ks * 32 + l4 * 8 + j) * 128 + n]);
        bw2[ks] = t;
    }
    const float wradv = w_e1[256 * 128 + n];
    const float b1v = b_e1[n], b2v = b_e2[n];

    const f32x4 z4 = {0.f, 0.f, 0.f, 0.f};
    const int colb = wv * 16 + (li >> 2) * 4;   // transposed col base
    const int pp   = li & 3;
    const int le   = tid >> 3;                  // edge slot this thread stages
    const int ch0  = tid & 7;                   // chunk group
    const int ntiles = NE / 64;
    const int tstep  = gridDim.x;

    // ---- prologue: gather first tile into registers ----
    short8 pf[4];
    {
        int e = elist[blockIdx.x * 64 + le];
        int r = ei[e], c = ei[NE + e];
        const unsigned short* hr = hb + (size_t)r * 128;
        const unsigned short* hc = hb + (size_t)c * 128;
        #pragma unroll
        for (int i = 0; i < 4; ++i) {
            int chunk = i * 8 + ch0;
            pf[i] = (chunk < 16) ? *(const short8*)(hr + chunk * 8)
                                 : *(const short8*)(hc + (chunk - 16) * 8);
        }
    }

    for (int t = blockIdx.x; t < ntiles; t += tstep) {
        const int ebase = t * 64;
        // ---- wave 0: edge ids, radial, segment table ----
        if (tid < 64) {
            int e = elist[ebase + tid];
            int r = ei[e], c = ei[NE + e];
            es_s[tid] = e;
            float dx = coord[r * 3 + 0] - coord[c * 3 + 0];
            float dy = coord[r * 3 + 1] - coord[c * 3 + 1];
            float dz = coord[r * 3 + 2] - coord[c * 3 + 2];
            rad[tid] = dx * dx + dy * dy + dz * dz;
            int prev = __shfl_up(r, 1);
            bool flag = (lane == 0) || (r != prev);
            unsigned long long mask = __ballot(flag);
            if (flag) {
                int pos = __popcll(mask & ((1ull << lane) - 1ull));
                seg_start[pos] = lane;
                seg_row[pos]   = r;
            }
            if (lane == 0) {
                int ns = __popcll(mask);
                nseg_s = ns;
                seg_start[ns] = 64;
            }
        }
        // ---- commit prefetched A1 tile: regs -> LDS ----
        #pragma unroll
        for (int i = 0; i < 4; ++i) {
            int chunk = i * 8 + ch0;
            int off = le * 512 + ((chunk * 16) ^ SWZ(le));
            *(short8*)((char*)A1s + off) = pf[i];
        }
        lds_barrier();   // B1

        // ---- issue next tile's gather (retires under G1/G2/seg-reduce) ----
        {
            int tn = t + tstep;
            if (tn < ntiles) {
                int e = elist[tn * 64 + le];
                int r = ei[e], c = ei[NE + e];
                const unsigned short* hr = hb + (size_t)r * 128;
                const unsigned short* hc = hb + (size_t)c * 128;
                #pragma unroll
                for (int i = 0; i < 4; ++i) {
                    int chunk = i * 8 + ch0;
                    pf[i] = (chunk < 16) ? *(const short8*)(hr + chunk * 8)
                                         : *(const short8*)(hc + (chunk - 16) * 8);
                }
            }
        }

        // ---- GEMM1: [64 x 256] @ [256 x 16] ----
        f32x4 acc[4];
        acc[0] = z4; acc[1] = z4; acc[2] = z4; acc[3] = z4;
        for (int ks = 0; ks < 8; ++ks) {
            const int kb = ks * 64 + l4 * 16;
            #pragma unroll
            for (int mf = 0; mf < 4; ++mf) {
                int row = mf * 16 + li;
                short8 a = *(const short8*)((const char*)A1s + row * 512 + (kb ^ SWZ(row)));
                acc[mf] = __builtin_amdgcn_mfma_f32_16x16x32_bf16(a, bw1[ks], acc[mf], 0, 0, 0);
            }
        }
        // epi1: bias + radial rank-1 + silu -> transpose -> packed b64 to A2s
        #pragma unroll
        for (int mf = 0; mf < 4; ++mf) {
            float4 rr = *(const float4*)&rad[mf * 16 + l4 * 4];
            float v[4];
            v[0] = silu_f(acc[mf][0] + rr.x * wradv + b1v);
            v[1] = silu_f(acc[mf][1] + rr.y * wradv + b1v);
            v[2] = silu_f(acc[mf][2] + rr.z * wradv + b1v);
            v[3] = silu_f(acc[mf][3] + rr.w * wradv + b1v);
            xpose4(v);
            int row = mf * 16 + l4 * 4 + pp;
            uint2 d;
            d.x = cvt_pk_bf16(v[0], v[1]);
            d.y = cvt_pk_bf16(v[2], v[3]);
            *(uint2*)((char*)A2s + row * 256 + ((colb * 2) ^ SWZ(row))) = d;
        }
        lds_barrier();   // B2: A2s ready; A1s reads done

        // ---- GEMM2: [64 x 128] @ [128 x 16] ----
        acc[0] = z4; acc[1] = z4; acc[2] = z4; acc[3] = z4;
        for (int ks = 0; ks < 4; ++ks) {
            const int kb = ks * 64 + l4 * 16;
            #pragma unroll
            for (int mf = 0; mf < 4; ++mf) {
                int row = mf * 16 + li;
                short8 a = *(const short8*)((const char*)A2s + row * 256 + (kb ^ SWZ(row)));
                acc[mf] = __builtin_amdgcn_mfma_f32_16x16x32_bf16(a, bw2[ks], acc[mf], 0, 0, 0);
            }
        }
        // epi2: bias+silu -> transpose -> EF b64 to A1s + ef f32x4 nt-store
        #pragma unroll
        for (int mf = 0; mf < 4; ++mf) {
            float v[4];
            v[0] = silu_f(acc[mf][0] + b2v);
            v[1] = silu_f(acc[mf][1] + b2v);
            v[2] = silu_f(acc[mf][2] + b2v);
            v[3] = silu_f(acc[mf][3] + b2v);
            xpose4(v);
            int row = mf * 16 + l4 * 4 + pp;
            uint2 d;
            d.x = cvt_pk_bf16(v[0], v[1]);
            d.y = cvt_pk_bf16(v[2], v[3]);
            *(uint2*)((char*)A1s + row * 256 + ((colb * 2) ^ SWZ(row))) = d;
            int e = es_s[row];
            f32x4 o = {v[0], v[1], v[2], v[3]};
            __builtin_nontemporal_store(o, (f32x4*)&ef[(size_t)e * 128 + colb]);
        }
        lds_barrier();   // B3: EF(A1s) complete

        // ---- seg-reduce: thread = (col-group of 4, seg slot) ----
        {
            const int cg = tid & 31;          // cols 4cg..4cg+3
            const int ns = nseg_s;
            for (int s = tid >> 5; s < ns; s += 16) {
                int i0 = seg_start[s], i1 = seg_start[s + 1];
                float s0 = 0.f, s1 = 0.f, s2 = 0.f, s3 = 0.f;
                for (int i = i0; i < i1; ++i) {
                    uint2 d = *(const uint2*)((const char*)A1s + i * 256 + ((cg * 8) ^ SWZ(i)));
                    s0 += __builtin_bit_cast(float, d.x << 16);
                    s1 += __builtin_bit_cast(float, d.x & 0xffff0000u);
                    s2 += __builtin_bit_cast(float, d.y << 16);
                    s3 += __builtin_bit_cast(float, d.y & 0xffff0000u);
                }
                float* ap = &agg[(size_t)seg_row[s] * 128 + cg * 4];
                atomicAdd(ap + 0, s0);
                atomicAdd(ap + 1, s1);
                atomicAdd(ap + 2, s2);
                atomicAdd(ap + 3, s3);
            }
        }
        lds_barrier();   // B4: A1s/seg reads done before next stage
    }
}

// ---------------------------------------------------------------------------
// K-coord: streaming coord MLP (original edge order).
//   wq = silu(ef @ w_c1 + b_c1) @ w_c2 ; tsum[row] += coord_diff * wq
// Swapped-operand GEMM: Wc1^T(A) x EF^T(B) -> edge lives in lane.
// 8 waves: edge-half (w&1)*64, feat-quarter (w>>1)*32. 2 lgkm barriers.
// ---------------------------------------------------------------------------
__global__ __launch_bounds__(512, 4) void k_coord(
    const float* __restrict__ ef, const float* __restrict__ coord,
    const int* __restrict__ ei,
    const float* __restrict__ w_c1, const float* __restrict__ b_c1,
    const float* __restrict__ w_c2,
    float* __restrict__ tsum)
{
    __shared__ unsigned short EFs[128 * 128];   // 32 KB, [edge][k] swizzled
    __shared__ float wqp[4][128];

    const int tid  = threadIdx.x;
    const int wv   = tid >> 6, lane = tid & 63;
    const int l4   = lane >> 4, li = lane & 15;
    const int eh   = (wv & 1) * 64;             // edge-half base
    const int fq   = (wv >> 1) * 32;            // feat-quarter base

    short8 wa[2][4];
    #pragma unroll
    for (int mf = 0; mf < 2; ++mf)
        #pragma unroll
        for (int ks = 0; ks < 4; ++ks) {
            short8 t;
            #pragma unroll
            for (int j = 0; j < 8; ++j)
                t[j] = f2bf(w_c1[(ks * 32 + l4 * 8 + j) * 128 + fq + mf * 16 + li]);
            wa[mf][ks] = t;
        }
    float bcv[2][4], wcv[2][4];
    #pragma unroll
    for (int mf = 0; mf < 2; ++mf)
        #pragma unroll
        for (int r = 0; r < 4; ++r) {
            int feat = fq + mf * 16 + l4 * 4 + r;
            bcv[mf][r] = b_c1[feat];
            wcv[mf][r] = w_c2[feat];
        }

    const f32x4 z4 = {0.f, 0.f, 0.f, 0.f};
    const int ntiles = (NE + 127) / 128;

    for (int t = blockIdx.x; t < ntiles; t += gridDim.x) {
        const int ebase = t * 128;
        // stage ef -> bf16 LDS: thread = (edge row tid>>2, 32-col chunk tid&3)
        {
            int row = tid >> 2;
            int e = ebase + row;
            int cb = (tid & 3) * 32;
            #pragma unroll
            for (int i = 0; i < 2; ++i) {
                int c0 = cb + i * 16;
                short8 v;
                if (e < NE) {
                    const float4* p = (const float4*)(ef + (size_t)e * 128 + c0);
                    float4 x = p[0], y = p[1];
                    v[0] = f2bf(x.x); v[1] = f2bf(x.y); v[2] = f2bf(x.z); v[3] = f2bf(x.w);
                    v[4] = f2bf(y.x); v[5] = f2bf(y.y); v[6] = f2bf(y.z); v[7] = f2bf(y.w);
                } else v = (short8)0;
                *(short8*)((char*)EFs + row * 256 + ((c0 * 2) ^ SWZ(row))) = v;
                int c1 = c0 + 8;
                short8 w;
                if (e < NE) {
                    const float4* q = (const float4*)(ef + (size_t)e * 128 + c1);
                    float4 x = q[0], y = q[1];
                    w[0] = f2bf(x.x); w[1] = f2bf(x.y); w[2] = f2bf(x.z); w[3] = f2bf(x.w);
                    w[4] = f2bf(y.x); w[5] = f2bf(y.y); w[6] = f2bf(y.z); w[7] = f2bf(y.w);
                } else w = (short8)0;
                *(short8*)((char*)EFs + row * 256 + ((c1 * 2) ^ SWZ(row))) = w;
            }
        }
        lds_barrier();   // B1

        f32x4 acc[2][4];
        #pragma unroll
        for (int mf = 0; mf < 2; ++mf)
            #pragma unroll
            for (int nf = 0; nf < 4; ++nf) acc[mf][nf] = z4;
        for (int ks = 0; ks < 4; ++ks) {
            const int kb = ks * 64 + l4 * 16;
            #pragma unroll
            for (int nf = 0; nf < 4; ++nf) {
                int edge = eh + nf * 16 + li;
                short8 b = *(const short8*)((const char*)EFs + edge * 256 + (kb ^ SWZ(edge)));
                #pragma unroll
                for (int mf = 0; mf < 2; ++mf)
                    acc[mf][nf] = __builtin_amdgcn_mfma_f32_16x16x32_bf16(
                        wa[mf][ks], b, acc[mf][nf], 0, 0, 0);
            }
        }
        #pragma unroll
        for (int nf = 0; nf < 4; ++nf) {
            float p = 0.f;
            #pragma unroll
            for (int mf = 0; mf < 2; ++mf)
                #pragma unroll
                for (int r = 0; r < 4; ++r)
                    p += silu_f(acc[mf][nf][r] + bcv[mf][r]) * wcv[mf][r];
            p += __shfl_xor(p, 16);
            p += __shfl_xor(p, 32);
            if (l4 == 0) wqp[wv >> 1][eh + nf * 16 + li] = p;
        }
        lds_barrier();   // B2

        if (tid < 128) {
            float wq = wqp[0][tid] + wqp[1][tid] + wqp[2][tid] + wqp[3][tid];
            int e = ebase + tid;
            if (e < NE) {
                int r = ei[e], c = ei[NE + e];
                float dx = coord[r * 3 + 0] - coord[c * 3 + 0];
                float dy = coord[r * 3 + 1] - coord[c * 3 + 1];
                float dz = coord[r * 3 + 2] - coord[c * 3 + 2];
                atomicAdd(&tsum[r * 3 + 0], dx * wq);
                atomicAdd(&tsum[r * 3 + 1], dy * wq);
                atomicAdd(&tsum[r * 3 + 2], dz * wq);
            }
        }
        // wqp re-written only after B1(t+1); EFs re-staged after B2 — safe.
    }
}

// ---------------------------------------------------------------------------
// K2: fused node MLP + coord_new. Packed epilogues, 2 lgkm barriers.
// ---------------------------------------------------------------------------
__global__ __launch_bounds__(512, 8) void k_node(
    const unsigned short* __restrict__ hb, const float* __restrict__ h,
    const float* __restrict__ agg,
    const float* __restrict__ w_n1, const float* __restrict__ b_n1,
    const float* __restrict__ w_n2, const float* __restrict__ b_n2,
    const float* __restrict__ coord, const float* __restrict__ tsum,
    const int* __restrict__ rowptr,
    float* __restrict__ h_new, float* __restrict__ coord_new)
{
    __shared__ unsigned short As[64 * 256];     // 32 KB
    __shared__ unsigned short Us[64 * 128];     // 16 KB

    const int tid  = threadIdx.x;
    const int wv   = tid >> 6, lane = tid & 63;
    const int l4   = lane >> 4, li = lane & 15;
    const int n    = wv * 16 + li;

    short8 bw1[8], bw2[4];
    #pragma unroll
    for (int ks = 0; ks < 8; ++ks) {
        short8 t;
        #pragma unroll
        for (int j = 0; j < 8; ++j) t[j] = f2bf(w_n1[(ks * 32 + l4 * 8 + j) * 128 + n]);
        bw1[ks] = t;
    }
    #pragma unroll
    for (int ks = 0; ks < 4; ++ks) {
        short8 t;
        #pragma unroll
        for (int j = 0; j < 8; ++j) t[j] = f2bf(w_n2[(ks * 32 + l4 * 8 + j) * 128 + n]);
        bw2[ks] = t;
    }
    const float b1v = b_n1[n], b2v = b_n2[n];

    const f32x4 z4 = {0.f, 0.f, 0.f, 0.f};
    const int ntiles = (NN + 63) / 64;
    const int colb = wv * 16 + (li >> 2) * 4;
    const int pp   = li & 3;

    for (int t = blockIdx.x; t < ntiles; t += gridDim.x) {
        const int nbase = t * 64;
        {
            int ln = tid >> 3;
            int node = nbase + ln;
            #pragma unroll
            for (int i = 0; i < 4; ++i) {
                int chunk = i * 8 + (tid & 7);
                short8 v;
                if (node < NN) {
                    if (chunk < 16) {
                        v = *(const short8*)(hb + (size_t)node * 128 + chunk * 8);
                    } else {
                        const float4* p = (const float4*)(agg + (size_t)node * 128 + (chunk - 16) * 8);
                        float4 x = p[0], y = p[1];
                        v[0] = f2bf(x.x); v[1] = f2bf(x.y); v[2] = f2bf(x.z); v[3] = f2bf(x.w);
                        v[4] = f2bf(y.x); v[5] = f2bf(y.y); v[6] = f2bf(y.z); v[7] = f2bf(y.w);
                    }
                } else v = (short8)0;
                int off = ln * 512 + ((chunk * 16) ^ SWZ(ln));
                *(short8*)((char*)As + off) = v;
            }
        }
        lds_barrier();   // B1

        f32x4 acc[4];
        acc[0] = z4; acc[1] = z4; acc[2] = z4; acc[3] = z4;
        for (int ks = 0; ks < 8; ++ks) {
            const int kb = ks * 64 + l4 * 16;
            #pragma unroll
            for (int mf = 0; mf < 4; ++mf) {
                int row = mf * 16 + li;
                short8 a = *(const short8*)((const char*)As + row * 512 + (kb ^ SWZ(row)));
                acc[mf] = __builtin_amdgcn_mfma_f32_16x16x32_bf16(a, bw1[ks], acc[mf], 0, 0, 0);
            }
        }
        #pragma unroll
        for (int mf = 0; mf < 4; ++mf) {
            float v[4];
            v[0] = silu_f(acc[mf][0] + b1v);
            v[1] = silu_f(acc[mf][1] + b1v);
            v[2] = silu_f(acc[mf][2] + b1v);
            v[3] = silu_f(acc[mf][3] + b1v);
            xpose4(v);
            int row = mf * 16 + l4 * 4 + pp;
            uint2 d;
            d.x = cvt_pk_bf16(v[0], v[1]);
            d.y = cvt_pk_bf16(v[2], v[3]);
            *(uint2*)((char*)Us + row * 256 + ((colb * 2) ^ SWZ(row))) = d;
        }
        lds_barrier();   // B2

        acc[0] = z4; acc[1] = z4; acc[2] = z4; acc[3] = z4;
        for (int ks = 0; ks < 4; ++ks) {
            const int kb = ks * 64 + l4 * 16;
            #pragma unroll
            for (int mf = 0; mf < 4; ++mf) {
                int row = mf * 16 + li;
                short8 a = *(const short8*)((const char*)Us + row * 256 + (kb ^ SWZ(row)));
                acc[mf] = __builtin_amdgcn_mfma_f32_16x16x32_bf16(a, bw2[ks], acc[mf], 0, 0, 0);
            }
        }
        #pragma unroll
        for (int mf = 0; mf < 4; ++mf) {
            float v[4];
            v[0] = acc[mf][0] + b2v;
            v[1] = acc[mf][1] + b2v;
            v[2] = acc[mf][2] + b2v;
            v[3] = acc[mf][3] + b2v;
            xpose4(v);
            int row = mf * 16 + l4 * 4 + pp;
            int node = nbase + row;
            if (node < NN) {
                const f32x4 h4 = *(const f32x4*)&h[(size_t)node * 128 + colb];
                f32x4 o = {v[0] + h4.x, v[1] + h4.y, v[2] + h4.z, v[3] + h4.w};
                __builtin_nontemporal_store(o, (f32x4*)&h_new[(size_t)node * 128 + colb]);
            }
        }
        if (tid < 64) {
            int node = nbase + tid;
            if (node < NN) {
                int deg = rowptr[node + 1] - rowptr[node];
                float m = fmaxf((float)deg, 1.0f);
                coord_new[node * 3 + 0] = coord[node * 3 + 0] + tsum[node * 3 + 0] / m;
                coord_new[node * 3 + 1] = coord[node * 3 + 1] + tsum[node * 3 + 1] / m;
                coord_new[node * 3 + 2] = coord[node * 3 + 2] + tsum[node * 3 + 2] / m;
            }
        }
    }
}

extern "C" void kernel_launch(void* const* d_in, const int* in_sizes, int n_in,
                              void* d_out, int out_size, void* d_ws, size_t ws_size,
                              hipStream_t stream)
{
    const float* h     = (const float*)d_in[0];
    const float* coord = (const float*)d_in[1];
    const int*   ei    = (const int*)d_in[2];
    const float* w_e1  = (const float*)d_in[3];
    const float* b_e1  = (const float*)d_in[4];
    const float* w_e2  = (const float*)d_in[5];
    const float* b_e2  = (const float*)d_in[6];
    const float* w_n1  = (const float*)d_in[7];
    const float* b_n1  = (const float*)d_in[8];
    const float* w_n2  = (const float*)d_in[9];
    const float* b_n2  = (const float*)d_in[10];
    const float* w_c1  = (const float*)d_in[11];
    const float* b_c1  = (const float*)d_in[12];
    const float* w_c2  = (const float*)d_in[13];

    float* h_new     = (float*)d_out;
    float* coord_new = h_new + (size_t)NN * 128;
    float* ef        = coord_new + (size_t)NN * 3;

    float*          agg    = (float*)d_ws;                              // [NN*128]
    float*          tsum   = agg + (size_t)NN * 128;                    // [NN*3]
    int*            deg    = (int*)(tsum + (size_t)NN * 3);             // [NN]
    int*            rowptr = deg + NN;                                  // [NN+1]
    int*            cursor = rowptr + NN + 1;                           // [NN]
    int*            elist  = cursor + NN;                               // [NE]
    unsigned short* hb     = (unsigned short*)(elist + NE);             // [NN*128]

    hipMemsetAsync(agg, 0, ((size_t)NN * 128 + (size_t)NN * 3 + NN) * sizeof(float), stream);

    k_prep   <<<1024, 512, 0, stream>>>(h, hb);
    k_deg    <<<1024, 256, 0, stream>>>(ei, deg);
    k_scan   <<<1,   1024, 0, stream>>>(deg, rowptr, cursor);
    k_scatter<<<1024, 256, 0, stream>>>(ei, cursor, elist);
    k_edge   <<<768,  512, 0, stream>>>(hb, coord, ei, elist, w_e1, b_e1,
                                        w_e2, b_e2, ef, agg);
    k_coord  <<<1536, 512, 0, stream>>>(ef, coord, ei, w_c1, b_c1, w_c2, tsum);
    k_node   <<<768,  512, 0, stream>>>(hb, h, agg, w_n1, b_n1, w_n2, b_n2,
                                        coord, tsum, rowptr, h_new, coord_new);
}